// Round 6
// baseline (462.382 us; speedup 1.0000x reference)
//
#include <hip/hip_runtime.h>
#include <hip/hip_fp16.h>

#define BB 4
#define SS 2048
#define HH 16
#define DKK 64
#define DMODEL 1024

typedef __attribute__((ext_vector_type(8))) _Float16 half8;
typedef __attribute__((ext_vector_type(4))) _Float16 half4;
typedef __attribute__((ext_vector_type(2))) __fp16 fp16x2;
typedef __attribute__((ext_vector_type(4))) float floatx4;

#define MFMA16(a, b, c) __builtin_amdgcn_mfma_f32_16x16x32_f16(a, b, c, 0, 0, 0)

// 8 * log2(e): reference scale is *8; softmax runs in exp2 domain.
// Folded into the Q projection epilogue (Qh is pre-scaled).
#define SCL2 11.5415603336f

// ---------------- async global->LDS, 16B per lane ------------------------------
__device__ __forceinline__ void gload_lds16(const _Float16* g, _Float16* l) {
    __builtin_amdgcn_global_load_lds(
        (const __attribute__((address_space(1))) void*)g,
        (__attribute__((address_space(3))) void*)l, 16, 0, 0);
}

// ---------------- cross-quad exchange via MODELED permlane builtins ------------
// R4's inline-asm version broke because a=b with identical values let the
// compiler coalesce both "+v" operands into ONE register -> self-swap rotated
// instead of exchanging. The builtins return both results ({vdst', vsrc'}) so
// the compiler models the dataflow correctly.
// permlane16_swap: vdst rows 1,3 (lanes 16-31,48-63) <-> vsrc rows 0,2
// permlane32_swap: vdst rows 2,3 (lanes 32-63) <-> vsrc rows 0,1
__device__ __forceinline__ float qred_max(float t) {
    unsigned u = __builtin_bit_cast(unsigned, t);
    auto r1 = __builtin_amdgcn_permlane16_swap(u, u, false, false);
    t = fmaxf(__builtin_bit_cast(float, (unsigned)r1[0]),
              __builtin_bit_cast(float, (unsigned)r1[1]));
    u = __builtin_bit_cast(unsigned, t);
    auto r2 = __builtin_amdgcn_permlane32_swap(u, u, false, false);
    return fmaxf(__builtin_bit_cast(float, (unsigned)r2[0]),
                 __builtin_bit_cast(float, (unsigned)r2[1]));
}
__device__ __forceinline__ float qred_sum(float t) {
    unsigned u = __builtin_bit_cast(unsigned, t);
    auto r1 = __builtin_amdgcn_permlane16_swap(u, u, false, false);
    t = __builtin_bit_cast(float, (unsigned)r1[0]) +
        __builtin_bit_cast(float, (unsigned)r1[1]);
    u = __builtin_bit_cast(unsigned, t);
    auto r2 = __builtin_amdgcn_permlane32_swap(u, u, false, false);
    return __builtin_bit_cast(float, (unsigned)r2[0]) +
           __builtin_bit_cast(float, (unsigned)r2[1]);
}

__device__ __forceinline__ unsigned pk(float a, float b) {
    return __builtin_bit_cast(unsigned, __builtin_amdgcn_cvt_pkrtz(a, b));
}

// In-register P redistribution: S^T accumulator layout (key=k2*16+quad*4+r,
// q=l16) -> PV B-operand layout (key=ks*32+quad*8+j, q=l16), for one ks.
// Inputs: X0=d0[2ks] X1=d1[2ks] Y0=d0[2ks+1] Y1=d1[2ks+1], where
// d0[k2]=pack(P[k2*16+quad*4+0],P[..+1]), d1[k2]=pack(P[..+2],P[..+3]).
// Step 1 (permlane32): route k2 halves -> 32-lane halves.
// Step 2 (permlane16): give each quad both its even/odd source-quad dwords.
// Verified elementwise: pf[j] = P[ks*32+quad*8+j][l16] for all (quad,j).
__device__ __forceinline__ half8 pshuffle(unsigned X0, unsigned X1,
                                          unsigned Y0, unsigned Y1) {
    auto a0 = __builtin_amdgcn_permlane32_swap(X0, Y0, false, false);
    auto a1 = __builtin_amdgcn_permlane32_swap(X1, Y1, false, false);
    auto b0 = __builtin_amdgcn_permlane16_swap(a0[0], a0[1], false, false);
    auto b1 = __builtin_amdgcn_permlane16_swap(a1[0], a1[1], false, false);
    union { unsigned u[4]; half8 h; } r;
    r.u[0] = b0[0]; r.u[1] = b1[0]; r.u[2] = b0[1]; r.u[3] = b1[1];
    return r.h;
}

// ---------------- fp32 -> fp16 convert of X body, k-unit XOR swizzle -----------
__device__ __forceinline__
void convert_x_body(const float* __restrict__ src, _Float16* __restrict__ dst,
                    int bidx)
{
    size_t base = ((size_t)bidx * 256 + threadIdx.x) * 8;
    int m = (int)(base >> 10);
    int kk = (int)(base & 1023);
    float4 a = *(const float4*)(src + base);
    float4 b = *(const float4*)(src + base + 4);
    half8 h;
    h[0] = (_Float16)a.x; h[1] = (_Float16)a.y; h[2] = (_Float16)a.z; h[3] = (_Float16)a.w;
    h[4] = (_Float16)b.x; h[5] = (_Float16)b.y; h[6] = (_Float16)b.z; h[7] = (_Float16)b.w;
    int kd = kk ^ ((m & 7) << 3);
    *(half8*)(dst + ((size_t)m << 10) + kd) = h;
}

// ---------------- W[k][n] -> WT[n][k] fp16 body, swizzle by (n&7) --------------
__device__ __forceinline__
void convert_wt_body(const float* __restrict__ W, _Float16* __restrict__ WT,
                     int bidx)
{
    __shared__ __attribute__((aligned(16))) _Float16 T[64][72];
    int kt = (bidx >> 4) << 6;
    int nt = (bidx & 15) << 6;
    int tid = threadIdx.x;
    #pragma unroll
    for (int p = 0; p < 4; p++) {
        int lin = tid + p * 256;
        int row = lin >> 4;
        int c4 = (lin & 15) << 2;
        float4 vv = *(const float4*)(W + (size_t)(kt + row) * DMODEL + nt + c4);
        T[c4 + 0][row] = (_Float16)vv.x;
        T[c4 + 1][row] = (_Float16)vv.y;
        T[c4 + 2][row] = (_Float16)vv.z;
        T[c4 + 3][row] = (_Float16)vv.w;
    }
    __syncthreads();
    #pragma unroll
    for (int p = 0; p < 2; p++) {
        int lin = tid + p * 256;
        int nl = lin >> 3;
        int u = lin & 7;
        half8 h = *(const half8*)&T[nl][u * 8];
        int n = nt + nl;
        int kd = kt + ((u ^ (n & 7)) << 3);
        *(half8*)(WT + (size_t)n * DMODEL + kd) = h;
    }
}

__global__ __launch_bounds__(256)
void convert_x(const float* __restrict__ q, const float* __restrict__ k,
               const float* __restrict__ v, _Float16* __restrict__ xq,
               _Float16* __restrict__ xk, _Float16* __restrict__ xv)
{
    int z = blockIdx.y;
    convert_x_body(z == 0 ? q : z == 1 ? k : v,
                   z == 0 ? xq : z == 1 ? xk : xv, blockIdx.x);
}

__global__ __launch_bounds__(256)
void convert_wt(const float* __restrict__ wq, const float* __restrict__ wk,
                const float* __restrict__ wv, _Float16* __restrict__ tq,
                _Float16* __restrict__ tk, _Float16* __restrict__ tv)
{
    int z = blockIdx.y;
    convert_wt_body(z == 0 ? wq : z == 1 ? wk : wv,
                    z == 0 ? tq : z == 1 ? tk : tv, blockIdx.x);
}

// fused converts: y=0..2 -> X converts; y=3 -> the 768 WT blocks
__global__ __launch_bounds__(256)
void convert_all(const float* __restrict__ q, const float* __restrict__ k,
                 const float* __restrict__ v, const float* __restrict__ wq,
                 const float* __restrict__ wk, const float* __restrict__ wv,
                 _Float16* __restrict__ xq, _Float16* __restrict__ xk,
                 _Float16* __restrict__ xv, _Float16* __restrict__ tq,
                 _Float16* __restrict__ tk, _Float16* __restrict__ tv)
{
    int y = blockIdx.y;
    if (y < 3) {
        convert_x_body(y == 0 ? q : y == 1 ? k : v,
                       y == 0 ? xq : y == 1 ? xk : xv, blockIdx.x);
    } else {
        if (blockIdx.x >= 768) return;
        int z = blockIdx.x >> 8;
        convert_wt_body(z == 0 ? wq : z == 1 ? wk : wv,
                        z == 0 ? tq : z == 1 ? tk : tv, blockIdx.x & 255);
    }
}

// ---------------- 128x128 projection GEMM body ---------------------------------
// XCD-aware tile map: the 8 n-blocks sharing one X m-tile all get the same
// bidx%8 -> same XCD. scl: epilogue scale ((acc+bias)*scl) -- SCL2 for Q.
// SWZ=1 pre-swizzles the stored K layout for flash3's LDS staging (rule #21:
// global_load_lds dest must stay linear, so the swizzle lives in the data):
//   VMODE=0 (K): d-block index ^= (s&7)   -> Ks ds_read conflict spread
// V (VMODE=1) is read global->VGPR in flash3, so it stays UNswizzled (SWZ=0).
template <int VMODE, int SWZ>
__device__ __forceinline__
void proj_body(const _Float16* __restrict__ X, const _Float16* __restrict__ WT,
               const float* __restrict__ bias, _Float16* __restrict__ out,
               int bidx, float scl)
{
    __shared__ __attribute__((aligned(16))) _Float16 As[128 * 64];
    __shared__ __attribute__((aligned(16))) _Float16 Bs[128 * 64];
    const int tid = threadIdx.x;
    const int wave = tid >> 6, lane = tid & 63, quad = lane >> 4, l16 = lane & 15;
    const int wm = wave >> 1, wn = wave & 1;
    const int m0 = ((bidx & 7) | ((bidx >> 6) << 3)) << 7;
    const int n0 = ((bidx >> 3) & 7) << 7;
    const int lrow = lane >> 3;
    const int lcol = (lane & 7) << 3;

    floatx4 acc[4][4] = {};

    for (int k0 = 0; k0 < DMODEL; k0 += 64) {
        __syncthreads();
        #pragma unroll
        for (int c = 0; c < 4; c++) {
            int row = c * 32 + wave * 8;
            gload_lds16(X + (size_t)(m0 + row + lrow) * DMODEL + k0 + lcol,
                        As + (size_t)row * 64);
            gload_lds16(WT + (size_t)(n0 + row + lrow) * DMODEL + k0 + lcol,
                        Bs + (size_t)row * 64);
        }
        __syncthreads();
        #pragma unroll
        for (int ks = 0; ks < 2; ks++) {
            int ccol = ((ks * 4 + quad) ^ (l16 & 7)) << 3;
            half8 af[4], bf[4];
            #pragma unroll
            for (int i = 0; i < 4; i++)
                af[i] = *(const half8*)(As + (wm * 64 + i * 16 + l16) * 64 + ccol);
            #pragma unroll
            for (int j = 0; j < 4; j++)
                bf[j] = *(const half8*)(Bs + (wn * 64 + j * 16 + l16) * 64 + ccol);
            #pragma unroll
            for (int i = 0; i < 4; i++)
                #pragma unroll
                for (int j = 0; j < 4; j++)
                    acc[i][j] = VMODE ? MFMA16(bf[j], af[i], acc[i][j])
                                      : MFMA16(af[i], bf[j], acc[i][j]);
        }
    }

    if (VMODE == 0) {
        #pragma unroll
        for (int j = 0; j < 4; j++) {
            int ng = n0 + wn * 64 + j * 16 + l16;
            int h = ng >> 6, d = ng & 63;
            float bv = bias[ng];
            #pragma unroll
            for (int i = 0; i < 4; i++)
                #pragma unroll
                for (int r = 0; r < 4; r++) {
                    int mg = m0 + wm * 64 + i * 16 + quad * 4 + r;
                    int bb = mg >> 11, s = mg & 2047;
                    int dd = SWZ ? ((((d >> 3) ^ (s & 7)) << 3) | (d & 7)) : d;
                    out[(((size_t)bb * HH + h) * SS + s) * DKK + dd] =
                        (_Float16)((acc[i][j][r] + bv) * scl);
                }
        }
    } else {
        #pragma unroll
        for (int j = 0; j < 4; j++)
            #pragma unroll
            for (int r = 0; r < 4; r++) {
                int ng = n0 + wn * 64 + j * 16 + quad * 4 + r;
                int h = ng >> 6, d = ng & 63;
                float bv = bias[ng];
                #pragma unroll
                for (int i = 0; i < 4; i++) {
                    int mg = m0 + wm * 64 + i * 16 + l16;
                    int bb = mg >> 11, s = mg & 2047;
                    int ss2 = SWZ ? (s ^ ((d & 7) << 3)) : s;
                    out[(((size_t)bb * HH + h) * DKK + d) * SS + ss2] =
                        (_Float16)((acc[i][j][r] + bv) * scl);
                }
            }
    }
}

template <int VMODE, int SWZ>
__global__ __launch_bounds__(256)
void proj128(const _Float16* __restrict__ X, const _Float16* __restrict__ WT,
             const float* __restrict__ bias, _Float16* __restrict__ out, float scl)
{
    proj_body<VMODE, SWZ>(X, WT, bias, out, blockIdx.x, scl);
}

// all three projections in one launch (requires non-aliased buffers)
__global__ __launch_bounds__(256)
void proj_all(const _Float16* __restrict__ Xq, const _Float16* __restrict__ Xk,
              const _Float16* __restrict__ Xv, const _Float16* __restrict__ WTq,
              const _Float16* __restrict__ WTk, const _Float16* __restrict__ WTv,
              const float* __restrict__ bq, const float* __restrict__ bk,
              const float* __restrict__ bv, _Float16* __restrict__ Qh,
              _Float16* __restrict__ Kh, _Float16* __restrict__ VTh)
{
    int z = blockIdx.y;
    if (z == 0)      proj_body<0, 0>(Xq, WTq, bq, Qh, blockIdx.x, SCL2);
    else if (z == 1) proj_body<0, 1>(Xk, WTk, bk, Kh, blockIdx.x, 1.0f);
    else             proj_body<1, 0>(Xv, WTv, bv, VTh, blockIdx.x, 1.0f);
}

// ---------------- flash attention v9: in-register P, 20KB LDS, 3 blocks/CU ----
// Softmax->PV now has NO LDS round-trip: the S^T->B-operand redistribution is
// done in-register with 4 permlane swaps per ks (pshuffle). Plds is deleted:
// LDS = Bias 4KB + Ks dbuf 16KB = 20KB -> 3 blocks/CU in the 64KB pool.
// Cross-quad softmax reductions also use permlane (VALU) instead of ds shfl.
// vmcnt queue discipline unchanged from v8 (counted waits, never drain).
__global__ __launch_bounds__(256)
void flash3(const _Float16* __restrict__ Qw, const _Float16* __restrict__ Kw,
            const _Float16* __restrict__ VTw, const int* __restrict__ mask,
            const float* __restrict__ resid, float* __restrict__ out)
{
    __shared__ _Float16 BiasH[SS];                                        // 4 KB
    __shared__ __attribute__((aligned(16))) _Float16 Ks[2][4096];         // 16 KB

    const int tid = threadIdx.x;
    const int wave = tid >> 6, lane = tid & 63, quad = lane >> 4, l16 = lane & 15;
    const int bx = blockIdx.x;
    const int xcd = bx & 7;
    const int jj = bx >> 3;
    const int bh = ((jj >> 4) << 3) | xcd;   // all 16 q-tiles of a bh on one XCD
    const int qt = jj & 15;
    const int b = bh >> 4;
    const int h = bh & 15;
    const int qbase = qt * 128 + wave * 32;
    const int sw = l16 & 7;

    const _Float16* Kbase = Kw + (size_t)bh * SS * DKK;
    const _Float16* Vbase = VTw + (size_t)bh * DKK * SS;

    // Q B-frags (oldest in the VMEM queue; drained by the first counted wait)
    half8 qf[2][2];
    #pragma unroll
    for (int mt = 0; mt < 2; mt++) {
        const _Float16* Qp = Qw + ((size_t)bh * SS + qbase + mt * 16 + l16) * DKK;
        qf[mt][0] = *(const half8*)(Qp + quad * 8);
        qf[mt][1] = *(const half8*)(Qp + 32 + quad * 8);
    }

    // prologue: stage K tile kt=0 (2 async DMA loads per thread)
    #pragma unroll
    for (int c = 0; c < 2; c++) {
        int chunk = wave * 2 + c;
        gload_lds16(Kbase + chunk * 512 + lane * 8, &Ks[0][chunk * 512]);
    }

    // stage mask -> fp16 additive bias (exp2 domain; -30000 kills)
    const int* mk = mask + b * SS;
    for (int i = tid; i < SS; i += 256)
        BiasH[i] = mk[i] ? (_Float16)0.0f : (_Float16)-30000.0f;
    // Bias visibility barrier WITHOUT draining vmcnt (keep DMA in flight)
    asm volatile("s_waitcnt lgkmcnt(0)" ::: "memory");
    __builtin_amdgcn_s_barrier();

    float mrow[2] = {-3.0e38f, -3.0e38f};
    float lrow[2] = {0.f, 0.f};
    floatx4 oacc[2][4] = {};   // O^T: [mt][dt]; col=l16=q, row=quad*4+r=d-local

    for (int kt = 0; kt < SS / 64; kt++) {
        const int cur = kt & 1;
        const _Float16* Kl = Ks[cur];
        const int kb = kt << 6;

        // V^T A-frags for THIS tile, issued FIRST (older than the K prefetch)
        half8 vf[2][4];
        #pragma unroll
        for (int ks = 0; ks < 2; ks++)
            #pragma unroll
            for (int dt = 0; dt < 4; dt++)
                vf[ks][dt] = *(const half8*)(Vbase
                    + (size_t)(dt * 16 + l16) * SS + kb + ks * 32 + quad * 8);

        // prefetch next K tile; counted wait drains ONLY ops older than this
        // iteration's 10 (8 vf + 2 dma) => current tile's K DMA has landed.
        if (kt < SS / 64 - 1) {
            const int kb1 = kb + 64;
            #pragma unroll
            for (int c = 0; c < 2; c++) {
                int chunk = wave * 2 + c;
                gload_lds16(Kbase + (size_t)kb1 * DKK + chunk * 512 + lane * 8,
                            &Ks[cur ^ 1][chunk * 512]);
            }
            asm volatile("s_waitcnt vmcnt(10)" ::: "memory");
        } else {
            asm volatile("s_waitcnt vmcnt(8)" ::: "memory");
        }
        __builtin_amdgcn_s_barrier();   // B1: Ks[cur] visible to all waves

        // acc init = mask bias (fp16 -> f32), keys kb + k2*16 + quad*4 + r
        floatx4 sacc[2][4];
        #pragma unroll
        for (int k2 = 0; k2 < 4; k2++) {
            half4 bh4 = *(const half4*)&BiasH[kb + k2 * 16 + quad * 4];
            floatx4 bi = {(float)bh4[0], (float)bh4[1], (float)bh4[2], (float)bh4[3]};
            sacc[0][k2] = bi;
            sacc[1][k2] = bi;
        }

        // QK^T with reduced kf live-range: one ks-slice of K at a time
        __builtin_amdgcn_s_setprio(1);
        #pragma unroll
        for (int ks = 0; ks < 2; ks++) {
            half8 kf[4];
            #pragma unroll
            for (int k2 = 0; k2 < 4; k2++)
                kf[k2] = *(const half8*)(Kl + (k2 * 16 + l16) * 64
                                + (((ks * 4 + quad) ^ sw) << 3));
            #pragma unroll
            for (int mt = 0; mt < 2; mt++)
                #pragma unroll
                for (int k2 = 0; k2 < 4; k2++)
                    sacc[mt][k2] = MFMA16(kf[k2], qf[mt][ks], sacc[mt][k2]);
        }
        __builtin_amdgcn_s_setprio(0);

        #pragma unroll
        for (int mt = 0; mt < 2; mt++) {
            floatx4* S = sacc[mt];

            // row max: depth-4 in-lane tree + cross-quad permlane butterflies
            float t4[4];
            #pragma unroll
            for (int k2 = 0; k2 < 4; k2++)
                t4[k2] = fmaxf(fmaxf(S[k2][0], S[k2][1]),
                               fmaxf(S[k2][2], S[k2][3]));
            float t = fmaxf(fmaxf(t4[0], t4[1]), fmaxf(t4[2], t4[3]));
            t = qred_max(t);

            float mn = fmaxf(mrow[mt], t);
            float al = exp2f(mrow[mt] - mn);
            mrow[mt] = mn;

            // exp2 in place; pack P pairs per k2 (d0 = keys +0,+1; d1 = +2,+3)
            unsigned d0[4], d1[4];
            float ss[4];
            #pragma unroll
            for (int k2 = 0; k2 < 4; k2++) {
                #pragma unroll
                for (int r = 0; r < 4; r++)
                    S[k2][r] = exp2f(S[k2][r] - mn);
                d0[k2] = pk(S[k2][0], S[k2][1]);
                d1[k2] = pk(S[k2][2], S[k2][3]);
                ss[k2] = (S[k2][0] + S[k2][1]) + (S[k2][2] + S[k2][3]);
            }

            // alpha rescale before accumulating this tile's PV
            #pragma unroll
            for (int dt = 0; dt < 4; dt++)
                oacc[mt][dt] *= al;

            // PV: O^T += V^T x P^T, P redistributed in-register (no LDS)
            __builtin_amdgcn_s_setprio(1);
            #pragma unroll
            for (int ks = 0; ks < 2; ks++) {
                half8 pf = pshuffle(d0[2 * ks], d1[2 * ks],
                                    d0[2 * ks + 1], d1[2 * ks + 1]);
                #pragma unroll
                for (int dt = 0; dt < 4; dt++)
                    oacc[mt][dt] = MFMA16(vf[ks][dt], pf, oacc[mt][dt]);
            }
            __builtin_amdgcn_s_setprio(0);

            // row-sum finish off the critical path (overlaps PV MFMAs)
            float ps = (ss[0] + ss[1]) + (ss[2] + ss[3]);
            ps = qred_sum(ps);
            lrow[mt] = lrow[mt] * al + ps;
        }
        __builtin_amdgcn_s_barrier();   // B2: all done reading Ks[cur]
    }

    // epilogue: float4 loads/stores
    #pragma unroll
    for (int mt = 0; mt < 2; mt++) {
        float rl = 1.0f / lrow[mt];
        int s = qbase + mt * 16 + l16;
        size_t rowoff = ((size_t)b * SS + s) * DMODEL + h * DKK;
        #pragma unroll
        for (int dt = 0; dt < 4; dt++) {
            size_t gi = rowoff + dt * 16 + quad * 4;
            float4 rv = *(const float4*)&resid[gi];
            float4 ov;
            ov.x = oacc[mt][dt][0] * rl + rv.x;
            ov.y = oacc[mt][dt][1] * rl + rv.y;
            ov.z = oacc[mt][dt][2] * rl + rv.z;
            ov.w = oacc[mt][dt][3] * rl + rv.w;
            *(float4*)&out[gi] = ov;
        }
    }
}

// ---------------------------------------------------------------------------
extern "C" void kernel_launch(void* const* d_in, const int* in_sizes, int n_in,
                              void* d_out, int out_size, void* d_ws, size_t ws_size,
                              hipStream_t stream)
{
    const float* q    = (const float*)d_in[0];
    const float* k    = (const float*)d_in[1];
    const float* v    = (const float*)d_in[2];
    const int*   mask = (const int*)d_in[3];
    const float* wq   = (const float*)d_in[4];
    const float* bq   = (const float*)d_in[5];
    const float* wk   = (const float*)d_in[6];
    const float* bk   = (const float*)d_in[7];
    const float* wv   = (const float*)d_in[8];
    const float* bv   = (const float*)d_in[9];
    float* out = (float*)d_out;

    const size_t TENS = (size_t)BB * SS * HH * DKK;   // 8388608 halves
    const size_t WSZ  = (size_t)DMODEL * DMODEL;      // 1048576 halves
    _Float16* base = (_Float16*)d_ws;

    bool big = ws_size >= (6 * TENS + 3 * WSZ) * sizeof(_Float16);
    _Float16 *Xq, *Xk, *Xv, *Qh, *Kh, *VTh, *WTq;
    if (big) {
        Xq = base;            Xk = base + TENS;     Xv = base + 2 * TENS;
        Qh = base + 3 * TENS; Kh = base + 4 * TENS; VTh = base + 5 * TENS;
        WTq = base + 6 * TENS;
    } else {
        // stream-ordered aliasing: Kh reuses Xq's slot, VTh reuses Xk's slot
        Xq = base;            Xk = base + TENS;     Xv = base + 2 * TENS;
        Qh = base + 3 * TENS; Kh = Xq;              VTh = Xk;
        WTq = base + 4 * TENS;
    }
    _Float16* WTk = WTq + WSZ;
    _Float16* WTv = WTk + WSZ;

    if (big) {
        hipLaunchKernelGGL(convert_all, dim3(4096, 4), dim3(256), 0, stream,
                           q, k, v, wq, wk, wv, Xq, Xk, Xv, WTq, WTk, WTv);
        hipLaunchKernelGGL(proj_all, dim3(512, 3), dim3(256), 0, stream,
                           Xq, Xk, Xv, WTq, WTk, WTv, bq, bk, bv, Qh, Kh, VTh);
    } else {
        hipLaunchKernelGGL(convert_x, dim3(4096, 3), dim3(256), 0, stream,
                           q, k, v, Xq, Xk, Xv);
        hipLaunchKernelGGL(convert_wt, dim3(256, 3), dim3(256), 0, stream,
                           wq, wk, wv, WTq, WTk, WTv);
        hipLaunchKernelGGL((proj128<0, 0>), dim3(512), dim3(256), 0, stream, Xq, WTq, bq, Qh, SCL2);
        hipLaunchKernelGGL((proj128<0, 1>), dim3(512), dim3(256), 0, stream, Xk, WTk, bk, Kh, 1.0f);
        hipLaunchKernelGGL((proj128<1, 0>), dim3(512), dim3(256), 0, stream, Xv, WTv, bv, VTh, 1.0f);
    }
    hipLaunchKernelGGL(flash3, dim3(BB * HH * (SS / 128)), dim3(256), 0, stream,
                       Qh, Kh, VTh, mask, q, out);
}

// Round 7
// 458.472 us; speedup vs baseline: 1.0085x; 1.0085x over previous
//
#include <hip/hip_runtime.h>
#include <hip/hip_fp16.h>

#define BB 4
#define SS 2048
#define HH 16
#define DKK 64
#define DMODEL 1024

typedef __attribute__((ext_vector_type(8))) _Float16 half8;
typedef __attribute__((ext_vector_type(4))) _Float16 half4;
typedef __attribute__((ext_vector_type(2))) __fp16 fp16x2;
typedef __attribute__((ext_vector_type(4))) float floatx4;

#define MFMA16(a, b, c) __builtin_amdgcn_mfma_f32_16x16x32_f16(a, b, c, 0, 0, 0)

// 8 * log2(e): reference scale is *8; softmax runs in exp2 domain.
// Folded into the Q projection epilogue (Qh is pre-scaled).
#define SCL2 11.5415603336f

// ---------------- async global->LDS, 16B per lane ------------------------------
__device__ __forceinline__ void gload_lds16(const _Float16* g, _Float16* l) {
    __builtin_amdgcn_global_load_lds(
        (const __attribute__((address_space(1))) void*)g,
        (__attribute__((address_space(3))) void*)l, 16, 0, 0);
}

// ---------------- cross-quad exchange via MODELED permlane builtins ------------
// (R6-proven correct.) permlane16_swap: lanes 16-31,48-63 of vdst <-> lanes
// 0-15,32-47 of vsrc; permlane32_swap: lanes 32-63 of vdst <-> 0-31 of vsrc.
__device__ __forceinline__ float qred_max(float t) {
    unsigned u = __builtin_bit_cast(unsigned, t);
    auto r1 = __builtin_amdgcn_permlane16_swap(u, u, false, false);
    t = fmaxf(__builtin_bit_cast(float, (unsigned)r1[0]),
              __builtin_bit_cast(float, (unsigned)r1[1]));
    u = __builtin_bit_cast(unsigned, t);
    auto r2 = __builtin_amdgcn_permlane32_swap(u, u, false, false);
    return fmaxf(__builtin_bit_cast(float, (unsigned)r2[0]),
                 __builtin_bit_cast(float, (unsigned)r2[1]));
}
__device__ __forceinline__ float qred_sum(float t) {
    unsigned u = __builtin_bit_cast(unsigned, t);
    auto r1 = __builtin_amdgcn_permlane16_swap(u, u, false, false);
    t = __builtin_bit_cast(float, (unsigned)r1[0]) +
        __builtin_bit_cast(float, (unsigned)r1[1]);
    u = __builtin_bit_cast(unsigned, t);
    auto r2 = __builtin_amdgcn_permlane32_swap(u, u, false, false);
    return __builtin_bit_cast(float, (unsigned)r2[0]) +
           __builtin_bit_cast(float, (unsigned)r2[1]);
}

__device__ __forceinline__ unsigned pk(float a, float b) {
    return __builtin_bit_cast(unsigned, __builtin_amdgcn_cvt_pkrtz(a, b));
}

// In-register P redistribution: S^T accumulator layout (key=k2*16+quad*4+r,
// q=l16) -> PV B-operand layout (key=ks*32+quad*8+j, q=l16), for one ks.
// (R6-proven correct.)
__device__ __forceinline__ half8 pshuffle(unsigned X0, unsigned X1,
                                          unsigned Y0, unsigned Y1) {
    auto a0 = __builtin_amdgcn_permlane32_swap(X0, Y0, false, false);
    auto a1 = __builtin_amdgcn_permlane32_swap(X1, Y1, false, false);
    auto b0 = __builtin_amdgcn_permlane16_swap(a0[0], a0[1], false, false);
    auto b1 = __builtin_amdgcn_permlane16_swap(a1[0], a1[1], false, false);
    union { unsigned u[4]; half8 h; } r;
    r.u[0] = b0[0]; r.u[1] = b1[0]; r.u[2] = b0[1]; r.u[3] = b1[1];
    return r.h;
}

// ---------------- fp32 -> fp16 convert of X body, k-unit XOR swizzle -----------
__device__ __forceinline__
void convert_x_body(const float* __restrict__ src, _Float16* __restrict__ dst,
                    int bidx)
{
    size_t base = ((size_t)bidx * 256 + threadIdx.x) * 8;
    int m = (int)(base >> 10);
    int kk = (int)(base & 1023);
    float4 a = *(const float4*)(src + base);
    float4 b = *(const float4*)(src + base + 4);
    half8 h;
    h[0] = (_Float16)a.x; h[1] = (_Float16)a.y; h[2] = (_Float16)a.z; h[3] = (_Float16)a.w;
    h[4] = (_Float16)b.x; h[5] = (_Float16)b.y; h[6] = (_Float16)b.z; h[7] = (_Float16)b.w;
    int kd = kk ^ ((m & 7) << 3);
    *(half8*)(dst + ((size_t)m << 10) + kd) = h;
}

// ---------------- mask -> f32 additive bias (global array) ---------------------
__device__ __forceinline__
void bias_body(const int* __restrict__ mk, float* __restrict__ bf, int lin)
{
    int idx = lin * 4;
    int4 m = *(const int4*)(mk + idx);
    float4 o;
    o.x = m.x ? 0.f : -30000.f;
    o.y = m.y ? 0.f : -30000.f;
    o.z = m.z ? 0.f : -30000.f;
    o.w = m.w ? 0.f : -30000.f;
    *(float4*)(bf + idx) = o;
}

// ---------------- W[k][n] -> WT[n][k] fp16 body, swizzle by (n&7) --------------
__device__ __forceinline__
void convert_wt_body(const float* __restrict__ W, _Float16* __restrict__ WT,
                     int bidx)
{
    __shared__ __attribute__((aligned(16))) _Float16 T[64][72];
    int kt = (bidx >> 4) << 6;
    int nt = (bidx & 15) << 6;
    int tid = threadIdx.x;
    #pragma unroll
    for (int p = 0; p < 4; p++) {
        int lin = tid + p * 256;
        int row = lin >> 4;
        int c4 = (lin & 15) << 2;
        float4 vv = *(const float4*)(W + (size_t)(kt + row) * DMODEL + nt + c4);
        T[c4 + 0][row] = (_Float16)vv.x;
        T[c4 + 1][row] = (_Float16)vv.y;
        T[c4 + 2][row] = (_Float16)vv.z;
        T[c4 + 3][row] = (_Float16)vv.w;
    }
    __syncthreads();
    #pragma unroll
    for (int p = 0; p < 2; p++) {
        int lin = tid + p * 256;
        int nl = lin >> 3;
        int u = lin & 7;
        half8 h = *(const half8*)&T[nl][u * 8];
        int n = nt + nl;
        int kd = kt + ((u ^ (n & 7)) << 3);
        *(half8*)(WT + (size_t)n * DMODEL + kd) = h;
    }
}

__global__ __launch_bounds__(256)
void convert_x(const float* __restrict__ q, const float* __restrict__ k,
               const float* __restrict__ v, _Float16* __restrict__ xq,
               _Float16* __restrict__ xk, _Float16* __restrict__ xv)
{
    int z = blockIdx.y;
    convert_x_body(z == 0 ? q : z == 1 ? k : v,
                   z == 0 ? xq : z == 1 ? xk : xv, blockIdx.x);
}

__global__ __launch_bounds__(256)
void convert_wt(const float* __restrict__ wq, const float* __restrict__ wk,
                const float* __restrict__ wv, _Float16* __restrict__ tq,
                _Float16* __restrict__ tk, _Float16* __restrict__ tv)
{
    int z = blockIdx.y;
    convert_wt_body(z == 0 ? wq : z == 1 ? wk : wv,
                    z == 0 ? tq : z == 1 ? tk : tv, blockIdx.x);
}

__global__ __launch_bounds__(256)
void convert_bias(const int* __restrict__ mk, float* __restrict__ bf)
{
    bias_body(mk, bf, blockIdx.x * 256 + threadIdx.x);
}

// fused converts: y=0..2 -> X converts; y=3 -> 768 WT blocks + 8 bias blocks
__global__ __launch_bounds__(256)
void convert_all(const float* __restrict__ q, const float* __restrict__ k,
                 const float* __restrict__ v, const float* __restrict__ wq,
                 const float* __restrict__ wk, const float* __restrict__ wv,
                 const int* __restrict__ mask,
                 _Float16* __restrict__ xq, _Float16* __restrict__ xk,
                 _Float16* __restrict__ xv, _Float16* __restrict__ tq,
                 _Float16* __restrict__ tk, _Float16* __restrict__ tv,
                 float* __restrict__ biasf)
{
    int y = blockIdx.y;
    if (y < 3) {
        convert_x_body(y == 0 ? q : y == 1 ? k : v,
                       y == 0 ? xq : y == 1 ? xk : xv, blockIdx.x);
    } else {
        if (blockIdx.x < 768) {
            int z = blockIdx.x >> 8;
            convert_wt_body(z == 0 ? wq : z == 1 ? wk : wv,
                            z == 0 ? tq : z == 1 ? tk : tv, blockIdx.x & 255);
        } else if (blockIdx.x < 776) {
            bias_body(mask, biasf, (blockIdx.x - 768) * 256 + threadIdx.x);
        }
    }
}

// ---------------- 128x128 projection GEMM body ---------------------------------
// XCD-aware tile map: the 8 n-blocks sharing one X m-tile all get the same
// bidx%8 -> same XCD. scl: epilogue scale ((acc+bias)*scl) -- SCL2 for Q.
// SWZ=1 pre-swizzles the stored K layout for flash3's LDS staging:
//   VMODE=0 (K): d-block index ^= (s&7)   -> Ks ds_read conflict spread
template <int VMODE, int SWZ>
__device__ __forceinline__
void proj_body(const _Float16* __restrict__ X, const _Float16* __restrict__ WT,
               const float* __restrict__ bias, _Float16* __restrict__ out,
               int bidx, float scl)
{
    __shared__ __attribute__((aligned(16))) _Float16 As[128 * 64];
    __shared__ __attribute__((aligned(16))) _Float16 Bs[128 * 64];
    const int tid = threadIdx.x;
    const int wave = tid >> 6, lane = tid & 63, quad = lane >> 4, l16 = lane & 15;
    const int wm = wave >> 1, wn = wave & 1;
    const int m0 = ((bidx & 7) | ((bidx >> 6) << 3)) << 7;
    const int n0 = ((bidx >> 3) & 7) << 7;
    const int lrow = lane >> 3;
    const int lcol = (lane & 7) << 3;

    floatx4 acc[4][4] = {};

    for (int k0 = 0; k0 < DMODEL; k0 += 64) {
        __syncthreads();
        #pragma unroll
        for (int c = 0; c < 4; c++) {
            int row = c * 32 + wave * 8;
            gload_lds16(X + (size_t)(m0 + row + lrow) * DMODEL + k0 + lcol,
                        As + (size_t)row * 64);
            gload_lds16(WT + (size_t)(n0 + row + lrow) * DMODEL + k0 + lcol,
                        Bs + (size_t)row * 64);
        }
        __syncthreads();
        #pragma unroll
        for (int ks = 0; ks < 2; ks++) {
            int ccol = ((ks * 4 + quad) ^ (l16 & 7)) << 3;
            half8 af[4], bf[4];
            #pragma unroll
            for (int i = 0; i < 4; i++)
                af[i] = *(const half8*)(As + (wm * 64 + i * 16 + l16) * 64 + ccol);
            #pragma unroll
            for (int j = 0; j < 4; j++)
                bf[j] = *(const half8*)(Bs + (wn * 64 + j * 16 + l16) * 64 + ccol);
            #pragma unroll
            for (int i = 0; i < 4; i++)
                #pragma unroll
                for (int j = 0; j < 4; j++)
                    acc[i][j] = VMODE ? MFMA16(bf[j], af[i], acc[i][j])
                                      : MFMA16(af[i], bf[j], acc[i][j]);
        }
    }

    if (VMODE == 0) {
        #pragma unroll
        for (int j = 0; j < 4; j++) {
            int ng = n0 + wn * 64 + j * 16 + l16;
            int h = ng >> 6, d = ng & 63;
            float bv = bias[ng];
            #pragma unroll
            for (int i = 0; i < 4; i++)
                #pragma unroll
                for (int r = 0; r < 4; r++) {
                    int mg = m0 + wm * 64 + i * 16 + quad * 4 + r;
                    int bb = mg >> 11, s = mg & 2047;
                    int dd = SWZ ? ((((d >> 3) ^ (s & 7)) << 3) | (d & 7)) : d;
                    out[(((size_t)bb * HH + h) * SS + s) * DKK + dd] =
                        (_Float16)((acc[i][j][r] + bv) * scl);
                }
        }
    } else {
        #pragma unroll
        for (int j = 0; j < 4; j++)
            #pragma unroll
            for (int r = 0; r < 4; r++) {
                int ng = n0 + wn * 64 + j * 16 + quad * 4 + r;
                int h = ng >> 6, d = ng & 63;
                float bv = bias[ng];
                #pragma unroll
                for (int i = 0; i < 4; i++) {
                    int mg = m0 + wm * 64 + i * 16 + l16;
                    int bb = mg >> 11, s = mg & 2047;
                    int ss2 = SWZ ? (s ^ ((d & 7) << 3)) : s;
                    out[(((size_t)bb * HH + h) * DKK + d) * SS + ss2] =
                        (_Float16)((acc[i][j][r] + bv) * scl);
                }
            }
    }
}

template <int VMODE, int SWZ>
__global__ __launch_bounds__(256)
void proj128(const _Float16* __restrict__ X, const _Float16* __restrict__ WT,
             const float* __restrict__ bias, _Float16* __restrict__ out, float scl)
{
    proj_body<VMODE, SWZ>(X, WT, bias, out, blockIdx.x, scl);
}

// all three projections in one launch (requires non-aliased buffers)
__global__ __launch_bounds__(256)
void proj_all(const _Float16* __restrict__ Xq, const _Float16* __restrict__ Xk,
              const _Float16* __restrict__ Xv, const _Float16* __restrict__ WTq,
              const _Float16* __restrict__ WTk, const _Float16* __restrict__ WTv,
              const float* __restrict__ bq, const float* __restrict__ bk,
              const float* __restrict__ bv, _Float16* __restrict__ Qh,
              _Float16* __restrict__ Kh, _Float16* __restrict__ VTh)
{
    int z = blockIdx.y;
    if (z == 0)      proj_body<0, 0>(Xq, WTq, bq, Qh, blockIdx.x, SCL2);
    else if (z == 1) proj_body<0, 1>(Xk, WTk, bk, Kh, blockIdx.x, 1.0f);
    else             proj_body<1, 0>(Xv, WTv, bv, VTh, blockIdx.x, 1.0f);
}

// ---------------- flash attention v10: 16KB LDS, f32 bias from global ----------
// LDS = Ks double-buffer ONLY (16384 B) -> targets 3-4 blocks/CU in the 64KB
// pool (8KB-granule model from R0/R2/R6 occupancy evidence). Bias is a
// precomputed f32 global array (L2-resident, 32KB): float4 loads init sacc
// directly -- no fp16 cvt VALU, no LDS. Exact alpha==1 skip when no row max
// grows. vmcnt queue: 14 ops/iter (8 vf + 4 bias + 2 dma); counted waits only.
__global__ __launch_bounds__(256)
void flash3(const _Float16* __restrict__ Qw, const _Float16* __restrict__ Kw,
            const _Float16* __restrict__ VTw, const float* __restrict__ BiasF,
            const float* __restrict__ resid, float* __restrict__ out)
{
    __shared__ __attribute__((aligned(16))) _Float16 Ks[2][4096];         // 16 KB

    const int tid = threadIdx.x;
    const int wave = tid >> 6, lane = tid & 63, quad = lane >> 4, l16 = lane & 15;
    const int bx = blockIdx.x;
    const int xcd = bx & 7;
    const int jj = bx >> 3;
    const int bh = ((jj >> 4) << 3) | xcd;   // all 16 q-tiles of a bh on one XCD
    const int qt = jj & 15;
    const int b = bh >> 4;
    const int h = bh & 15;
    const int qbase = qt * 128 + wave * 32;
    const int sw = l16 & 7;

    const _Float16* Kbase = Kw + (size_t)bh * SS * DKK;
    const _Float16* Vbase = VTw + (size_t)bh * DKK * SS;
    const float*    Bf    = BiasF + (size_t)b * SS;

    // Q B-frags (oldest in the VMEM queue; drained by the first counted wait)
    half8 qf[2][2];
    #pragma unroll
    for (int mt = 0; mt < 2; mt++) {
        const _Float16* Qp = Qw + ((size_t)bh * SS + qbase + mt * 16 + l16) * DKK;
        qf[mt][0] = *(const half8*)(Qp + quad * 8);
        qf[mt][1] = *(const half8*)(Qp + 32 + quad * 8);
    }

    // prologue: stage K tile kt=0 (2 async DMA loads per thread)
    #pragma unroll
    for (int c = 0; c < 2; c++) {
        int chunk = wave * 2 + c;
        gload_lds16(Kbase + chunk * 512 + lane * 8, &Ks[0][chunk * 512]);
    }

    float mrow[2] = {-3.0e38f, -3.0e38f};
    float lrow[2] = {0.f, 0.f};
    floatx4 oacc[2][4] = {};   // O^T: [mt][dt]; col=l16=q, row=quad*4+r=d-local

    for (int kt = 0; kt < SS / 64; kt++) {
        const int cur = kt & 1;
        const _Float16* Kl = Ks[cur];
        const int kb = kt << 6;

        // V^T A-frags for THIS tile, issued FIRST (oldest this iteration)
        half8 vf[2][4];
        #pragma unroll
        for (int ks = 0; ks < 2; ks++)
            #pragma unroll
            for (int dt = 0; dt < 4; dt++)
                vf[ks][dt] = *(const half8*)(Vbase
                    + (size_t)(dt * 16 + l16) * SS + kb + ks * 32 + quad * 8);

        // f32 bias loads (L2-resident; shared by both mt)
        float4 bs4[4];
        #pragma unroll
        for (int k2 = 0; k2 < 4; k2++)
            bs4[k2] = *(const float4*)(Bf + kb + k2 * 16 + quad * 4);

        // prefetch next K tile; counted wait drains ONLY ops older than this
        // iteration's 14 (8 vf + 4 bias + 2 dma) => Ks[cur]'s DMA has landed.
        if (kt < SS / 64 - 1) {
            const int kb1 = kb + 64;
            #pragma unroll
            for (int c = 0; c < 2; c++) {
                int chunk = wave * 2 + c;
                gload_lds16(Kbase + (size_t)kb1 * DKK + chunk * 512 + lane * 8,
                            &Ks[cur ^ 1][chunk * 512]);
            }
            asm volatile("s_waitcnt vmcnt(14)" ::: "memory");
        } else {
            asm volatile("s_waitcnt vmcnt(12)" ::: "memory");
        }
        __builtin_amdgcn_s_barrier();   // B1: Ks[cur] visible to all waves

        // acc init = mask bias (f32, no conversion)
        floatx4 sacc[2][4];
        #pragma unroll
        for (int k2 = 0; k2 < 4; k2++) {
            floatx4 bi = {bs4[k2].x, bs4[k2].y, bs4[k2].z, bs4[k2].w};
            sacc[0][k2] = bi;
            sacc[1][k2] = bi;
        }

        // QK^T with reduced kf live-range: one ks-slice of K at a time
        __builtin_amdgcn_s_setprio(1);
        #pragma unroll
        for (int ks = 0; ks < 2; ks++) {
            half8 kf[4];
            #pragma unroll
            for (int k2 = 0; k2 < 4; k2++)
                kf[k2] = *(const half8*)(Kl + (k2 * 16 + l16) * 64
                                + (((ks * 4 + quad) ^ sw) << 3));
            #pragma unroll
            for (int mt = 0; mt < 2; mt++)
                #pragma unroll
                for (int k2 = 0; k2 < 4; k2++)
                    sacc[mt][k2] = MFMA16(kf[k2], qf[mt][ks], sacc[mt][k2]);
        }
        __builtin_amdgcn_s_setprio(0);

        #pragma unroll
        for (int mt = 0; mt < 2; mt++) {
            floatx4* S = sacc[mt];

            // row max: depth-4 in-lane tree + cross-quad permlane butterflies
            float t4[4];
            #pragma unroll
            for (int k2 = 0; k2 < 4; k2++)
                t4[k2] = fmaxf(fmaxf(S[k2][0], S[k2][1]),
                               fmaxf(S[k2][2], S[k2][3]));
            float t = fmaxf(fmaxf(t4[0], t4[1]), fmaxf(t4[2], t4[3]));
            t = qred_max(t);

            // exact skip: alpha == 1 when no row in the wave saw a new max
            float mn = mrow[mt];
            if (__any(t > mn)) {
                mn = fmaxf(mn, t);
                float al = exp2f(mrow[mt] - mn);
                mrow[mt] = mn;
                lrow[mt] *= al;
                #pragma unroll
                for (int dt = 0; dt < 4; dt++)
                    oacc[mt][dt] *= al;
            }

            // exp2 in place; pack P pairs per k2 (d0 = keys +0,+1; d1 = +2,+3)
            unsigned d0[4], d1[4];
            float ss[4];
            #pragma unroll
            for (int k2 = 0; k2 < 4; k2++) {
                #pragma unroll
                for (int r = 0; r < 4; r++)
                    S[k2][r] = exp2f(S[k2][r] - mn);
                d0[k2] = pk(S[k2][0], S[k2][1]);
                d1[k2] = pk(S[k2][2], S[k2][3]);
                ss[k2] = (S[k2][0] + S[k2][1]) + (S[k2][2] + S[k2][3]);
            }

            // PV: O^T += V^T x P^T, P redistributed in-register (no LDS)
            __builtin_amdgcn_s_setprio(1);
            #pragma unroll
            for (int ks = 0; ks < 2; ks++) {
                half8 pf = pshuffle(d0[2 * ks], d1[2 * ks],
                                    d0[2 * ks + 1], d1[2 * ks + 1]);
                #pragma unroll
                for (int dt = 0; dt < 4; dt++)
                    oacc[mt][dt] = MFMA16(vf[ks][dt], pf, oacc[mt][dt]);
            }
            __builtin_amdgcn_s_setprio(0);

            // row-sum finish off the critical path (overlaps PV MFMAs)
            float ps = (ss[0] + ss[1]) + (ss[2] + ss[3]);
            ps = qred_sum(ps);
            lrow[mt] += ps;
        }
        __builtin_amdgcn_s_barrier();   // B2: all done reading Ks[cur]
    }

    // epilogue: float4 loads/stores
    #pragma unroll
    for (int mt = 0; mt < 2; mt++) {
        float rl = 1.0f / lrow[mt];
        int s = qbase + mt * 16 + l16;
        size_t rowoff = ((size_t)b * SS + s) * DMODEL + h * DKK;
        #pragma unroll
        for (int dt = 0; dt < 4; dt++) {
            size_t gi = rowoff + dt * 16 + quad * 4;
            float4 rv = *(const float4*)&resid[gi];
            float4 ov;
            ov.x = oacc[mt][dt][0] * rl + rv.x;
            ov.y = oacc[mt][dt][1] * rl + rv.y;
            ov.z = oacc[mt][dt][2] * rl + rv.z;
            ov.w = oacc[mt][dt][3] * rl + rv.w;
            *(float4*)&out[gi] = ov;
        }
    }
}

// ---------------------------------------------------------------------------
extern "C" void kernel_launch(void* const* d_in, const int* in_sizes, int n_in,
                              void* d_out, int out_size, void* d_ws, size_t ws_size,
                              hipStream_t stream)
{
    const float* q    = (const float*)d_in[0];
    const float* k    = (const float*)d_in[1];
    const float* v    = (const float*)d_in[2];
    const int*   mask = (const int*)d_in[3];
    const float* wq   = (const float*)d_in[4];
    const float* bq   = (const float*)d_in[5];
    const float* wk   = (const float*)d_in[6];
    const float* bk   = (const float*)d_in[7];
    const float* wv   = (const float*)d_in[8];
    const float* bv   = (const float*)d_in[9];
    float* out = (float*)d_out;

    const size_t TENS = (size_t)BB * SS * HH * DKK;   // 8388608 halves
    const size_t WSZ  = (size_t)DMODEL * DMODEL;      // 1048576 halves
    const size_t BIASF = (size_t)BB * SS;             // 8192 floats
    _Float16* base = (_Float16*)d_ws;

    bool big = ws_size >= (6 * TENS + 3 * WSZ) * sizeof(_Float16)
                         + BIASF * sizeof(float);
    _Float16 *Xq, *Xk, *Xv, *Qh, *Kh, *VTh, *WTq;
    if (big) {
        Xq = base;            Xk = base + TENS;     Xv = base + 2 * TENS;
        Qh = base + 3 * TENS; Kh = base + 4 * TENS; VTh = base + 5 * TENS;
        WTq = base + 6 * TENS;
    } else {
        // stream-ordered aliasing: Kh reuses Xq's slot, VTh reuses Xk's slot
        Xq = base;            Xk = base + TENS;     Xv = base + 2 * TENS;
        Qh = base + 3 * TENS; Kh = Xq;              VTh = Xk;
        WTq = base + 4 * TENS;
    }
    _Float16* WTk = WTq + WSZ;
    _Float16* WTv = WTk + WSZ;
    float* BiasF = (float*)(WTv + WSZ);

    if (big) {
        hipLaunchKernelGGL(convert_all, dim3(4096, 4), dim3(256), 0, stream,
                           q, k, v, wq, wk, wv, mask,
                           Xq, Xk, Xv, WTq, WTk, WTv, BiasF);
        hipLaunchKernelGGL(proj_all, dim3(512, 3), dim3(256), 0, stream,
                           Xq, Xk, Xv, WTq, WTk, WTv, bq, bk, bv, Qh, Kh, VTh);
    } else {
        hipLaunchKernelGGL(convert_x, dim3(4096, 3), dim3(256), 0, stream,
                           q, k, v, Xq, Xk, Xv);
        hipLaunchKernelGGL(convert_wt, dim3(256, 3), dim3(256), 0, stream,
                           wq, wk, wv, WTq, WTk, WTv);
        hipLaunchKernelGGL(convert_bias, dim3(8), dim3(256), 0, stream, mask, BiasF);
        hipLaunchKernelGGL((proj128<0, 0>), dim3(512), dim3(256), 0, stream, Xq, WTq, bq, Qh, SCL2);
        hipLaunchKernelGGL((proj128<0, 1>), dim3(512), dim3(256), 0, stream, Xk, WTk, bk, Kh, 1.0f);
        hipLaunchKernelGGL((proj128<1, 0>), dim3(512), dim3(256), 0, stream, Xv, WTv, bv, VTh, 1.0f);
    }
    hipLaunchKernelGGL(flash3, dim3(BB * HH * (SS / 128)), dim3(256), 0, stream,
                       Qh, Kh, VTh, BiasF, q, out);
}